// Round 11
// baseline (445.710 us; speedup 1.0000x reference)
//
#include <hip/hip_runtime.h>
#include <hip/hip_fp16.h>

// MEASUREMENT ROUND: identical kernel to round 10, launched 3x per call
// (idempotent -> output identical). dur_us delta vs round 10 (363.3us) = 2x
// true kernel duration, separating kernel cost from harness restore/poison
// overhead (~320us suspected). If delta/2 <= ~45us the kernel has been at the
// HBM roofline since round 8.

#define S_LEN 8192
#define NH    8
#define DH    128
#define ROW4  (NH * DH / 4)     // 256 float4 per position
#define PPW   16                // positions per wave
#define WSTRIDE (S_LEN / PPW)   // 512
#define BLK   256               // 4 waves

__global__ __launch_bounds__(BLK) void qk_decode_kernel(
    const float4* __restrict__ K4,  // (b, S, H, D/4)
    const float4* __restrict__ Q4,  // (b, 1, H, D/4)
    const int* __restrict__ sp,
    const int* __restrict__ sl,
    float* __restrict__ out)        // (b, H, 1, S) f32
{
    const int lane = threadIdx.x & 63;
    const int wid  = threadIdx.x >> 6;
    const int b    = blockIdx.y;
    const int w    = blockIdx.x * 4 + wid;   // wave index within batch: [0,512)

    float4 qr[4];
#pragma unroll
    for (int g = 0; g < 4; ++g)
        qr[g] = Q4[b * ROW4 + g * 64 + lane];

    const int   total   = sp[0] + sl[0];
    const float scale   = 0.08838834764831845f;  // 1/sqrt(128)
    const int   halfsel = lane >> 5;
    const bool  writer  = (lane & 31) == 0;      // lanes 0 and 32

    const float4* kbase = K4 + (size_t)b * S_LEN * ROW4;

#pragma unroll 2
    for (int ps = 0; ps < PPW; ++ps) {
        const int s = w + ps * WSTRIDE;
        const float4* row = kbase + (size_t)s * ROW4;

        float part[4];
#pragma unroll
        for (int g = 0; g < 4; ++g) {
            float4 v = row[g * 64 + lane];       // wave: contiguous 1KB
            part[g] = v.x * qr[g].x + v.y * qr[g].y + v.z * qr[g].z + v.w * qr[g].w;
        }

#pragma unroll
        for (int g = 0; g < 4; ++g) {
            float p = part[g];
            p += __shfl_xor(p, 1);
            p += __shfl_xor(p, 2);
            p += __shfl_xor(p, 4);
            p += __shfl_xor(p, 8);
            p += __shfl_xor(p, 16);
            if (writer) {
                float o = (s < total)
                        ? __half2float(__float2half(p * scale))
                        : -INFINITY;
                out[((size_t)b * NH + 2 * g + halfsel) * S_LEN + s] = o;
            }
        }
    }
}

extern "C" void kernel_launch(void* const* d_in, const int* in_sizes, int n_in,
                              void* d_out, int out_size, void* d_ws, size_t ws_size,
                              hipStream_t stream) {
    const float4* K4 = (const float4*)d_in[0];
    const float4* Q4 = (const float4*)d_in[1];
    const int*    sp = (const int*)d_in[2];
    const int*    sl = (const int*)d_in[3];
    float* out = (float*)d_out;

    dim3 grid(S_LEN / (PPW * 4), 8 /*bsz*/);    // 1024 blocks, 16 waves/CU
    dim3 block(BLK);
    // 3 identical launches: timing probe (delta vs single launch = 2x kernel).
    qk_decode_kernel<<<grid, block, 0, stream>>>(K4, Q4, sp, sl, out);
    qk_decode_kernel<<<grid, block, 0, stream>>>(K4, Q4, sp, sl, out);
    qk_decode_kernel<<<grid, block, 0, stream>>>(K4, Q4, sp, sl, out);
}

// Round 12
// 362.523 us; speedup vs baseline: 1.2295x; 1.2295x over previous
//
#include <hip/hip_runtime.h>
#include <hip/hip_fp16.h>

// Collapsed op: out[b,h,0,p] = dot(q[b,0,h,:], K[b,p,h,:]) * rsqrt(128),
// -inf for p >= start_pos+seqlen (no-op: total = 8192 = S).
// K,Q = float32 (fp16-upcast), out = float32 (fp16-rounded). PROVEN round 5.
//
// ROOFLINE-CONFIRMED (round 11 3x-launch probe): true kernel time ~41us =
// 268.4MB compulsory read @ ~6.6TB/s effective (>= 6.3TB/s achievable HBM
// ceiling; compulsory traffic, zero reuse possible). Remaining dur_us (~320us)
// is harness restore/poison overhead, outside kernel control.
// Wave-coalesced: each wave reads one position's 4KB row as contiguous
// 16B/lane chunks; dot via 5-level shfl_xor within 32-lane halves.

#define S_LEN 8192
#define NH    8
#define DH    128
#define ROW4  (NH * DH / 4)     // 256 float4 per position
#define PPW   16                // positions per wave
#define WSTRIDE (S_LEN / PPW)   // 512
#define BLK   256               // 4 waves

__global__ __launch_bounds__(BLK) void qk_decode_kernel(
    const float4* __restrict__ K4,  // (b, S, H, D/4)
    const float4* __restrict__ Q4,  // (b, 1, H, D/4)
    const int* __restrict__ sp,
    const int* __restrict__ sl,
    float* __restrict__ out)        // (b, H, 1, S) f32
{
    const int lane = threadIdx.x & 63;
    const int wid  = threadIdx.x >> 6;
    const int b    = blockIdx.y;
    const int w    = blockIdx.x * 4 + wid;   // wave index within batch: [0,512)

    float4 qr[4];
#pragma unroll
    for (int g = 0; g < 4; ++g)
        qr[g] = Q4[b * ROW4 + g * 64 + lane];

    const int   total   = sp[0] + sl[0];
    const float scale   = 0.08838834764831845f;  // 1/sqrt(128)
    const int   halfsel = lane >> 5;
    const bool  writer  = (lane & 31) == 0;      // lanes 0 and 32

    const float4* kbase = K4 + (size_t)b * S_LEN * ROW4;

#pragma unroll 2
    for (int ps = 0; ps < PPW; ++ps) {
        const int s = w + ps * WSTRIDE;
        const float4* row = kbase + (size_t)s * ROW4;

        float part[4];
#pragma unroll
        for (int g = 0; g < 4; ++g) {
            float4 v = row[g * 64 + lane];       // wave: contiguous 1KB
            part[g] = v.x * qr[g].x + v.y * qr[g].y + v.z * qr[g].z + v.w * qr[g].w;
        }

#pragma unroll
        for (int g = 0; g < 4; ++g) {
            float p = part[g];
            p += __shfl_xor(p, 1);
            p += __shfl_xor(p, 2);
            p += __shfl_xor(p, 4);
            p += __shfl_xor(p, 8);
            p += __shfl_xor(p, 16);
            if (writer) {
                float o = (s < total)
                        ? __half2float(__float2half(p * scale))
                        : -INFINITY;
                out[((size_t)b * NH + 2 * g + halfsel) * S_LEN + s] = o;
            }
        }
    }
}

extern "C" void kernel_launch(void* const* d_in, const int* in_sizes, int n_in,
                              void* d_out, int out_size, void* d_ws, size_t ws_size,
                              hipStream_t stream) {
    const float4* K4 = (const float4*)d_in[0];
    const float4* Q4 = (const float4*)d_in[1];
    const int*    sp = (const int*)d_in[2];
    const int*    sl = (const int*)d_in[3];
    float* out = (float*)d_out;

    dim3 grid(S_LEN / (PPW * 4), 8 /*bsz*/);    // 1024 blocks, 16 waves/CU
    dim3 block(BLK);
    qk_decode_kernel<<<grid, block, 0, stream>>>(K4, Q4, sp, sl, out);
}